// Round 1
// baseline (670.177 us; speedup 1.0000x reference)
//
#include <hip/hip_runtime.h>
#include <hip/hip_bf16.h>

// Problem constants
constexpr int Bc = 2, Sc = 1024, Ec = 1024, Hc = 16, HDc = 64;
constexpr float SCALE = 0.125f; // HD^-0.5

// ---------------------------------------------------------------------------
// K1: pre_softmax[b,h,q,k] = s + relu(s*w0 + aid·w + bias)*aid_scale,
//     s = (q·k) * SCALE
// grid: dim3(64, 32) = ((S/128)*(S/128), B*H), block 256
// ---------------------------------------------------------------------------
__global__ __launch_bounds__(256, 2) void k_scores(
    const float* __restrict__ Q, const float* __restrict__ Kp,
    const float* __restrict__ aid, const float* __restrict__ mw,
    const float* __restrict__ mb, const float* __restrict__ ascale,
    float* __restrict__ pre)
{
    __shared__ float Qs[128][HDc];
    __shared__ float Ks[128][HDc];

    const int bh = blockIdx.y;
    const int b  = bh >> 4;
    const int h  = bh & 15;
    const int qt = (blockIdx.x >> 3) * 128;
    const int kt = (blockIdx.x & 7) * 128;

    const float* Qbase = Q  + (size_t)b * Sc * Ec + (size_t)h * Sc * HDc;
    const float* Kbase = Kp + (size_t)b * Sc * Ec + (size_t)h * Sc * HDc;

    const int tid = threadIdx.x;

    // Stage 128x64 tiles of Q and K (8192 floats each -> 8 float4/thread)
    #pragma unroll
    for (int i = 0; i < 8; ++i) {
        int idx = tid + i * 256;         // float4 index
        int r = idx >> 4;
        int c = (idx & 15) << 2;
        *(float4*)&Qs[r][c] = *(const float4*)&Qbase[(size_t)(qt + r) * HDc + c];
        *(float4*)&Ks[r][c] = *(const float4*)&Kbase[(size_t)(kt + r) * HDc + c];
    }
    __syncthreads();

    const int ty = tid >> 4, tx = tid & 15;
    const int qr = ty * 8, kc = tx * 8;

    float acc[8][8] = {};
    #pragma unroll
    for (int d = 0; d < HDc; d += 4) {
        float qv[8][4], kv[8][4];
        #pragma unroll
        for (int r = 0; r < 8; ++r) *(float4*)qv[r] = *(const float4*)&Qs[qr + r][d];
        #pragma unroll
        for (int c = 0; c < 8; ++c) *(float4*)kv[c] = *(const float4*)&Ks[kc + c][d];
        #pragma unroll
        for (int r = 0; r < 8; ++r)
            #pragma unroll
            for (int c = 0; c < 8; ++c)
                #pragma unroll
                for (int j = 0; j < 4; ++j)
                    acc[r][c] += qv[r][j] * kv[c][j];
    }

    const float w0 = mw[h * 4 + 0], w1 = mw[h * 4 + 1];
    const float w2 = mw[h * 4 + 2], w3 = mw[h * 4 + 3];
    const float bias = mb[h];
    const float asc  = ascale[0];

    const size_t prebase = (size_t)bh * Sc * Sc;

    #pragma unroll
    for (int r = 0; r < 8; ++r) {
        const int qq = qt + qr + r;
        const float* arow = aid + ((size_t)b * Sc + qq) * Sc * 3;
        // load 24 consecutive aid floats covering our 8 k-columns
        float a24[24];
        {
            const float4* src = (const float4*)&arow[(size_t)(kt + kc) * 3];
            float4* dst4 = (float4*)a24;
            #pragma unroll
            for (int j = 0; j < 6; ++j) dst4[j] = src[j];
        }
        float o[8];
        #pragma unroll
        for (int c = 0; c < 8; ++c) {
            float s = acc[r][c] * SCALE;
            float m = s * w0 + a24[c * 3 + 0] * w1 + a24[c * 3 + 1] * w2
                    + a24[c * 3 + 2] * w3 + bias;
            o[c] = s + fmaxf(m, 0.f) * asc;
        }
        float4* dst = (float4*)&pre[prebase + (size_t)qq * Sc + kt + kc];
        dst[0] = make_float4(o[0], o[1], o[2], o[3]);
        dst[1] = make_float4(o[4], o[5], o[6], o[7]);
    }
}

// ---------------------------------------------------------------------------
// K2: row softmax. One wave per row of 1024. grid: B*H*S/4 blocks, block 256.
// ---------------------------------------------------------------------------
__global__ __launch_bounds__(256) void k_softmax(
    const float* __restrict__ pre, float* __restrict__ attn)
{
    const int row  = blockIdx.x * 4 + (threadIdx.x >> 6);
    const int lane = threadIdx.x & 63;

    const float* src = pre + (size_t)row * Sc;
    float v[4][4];
    float m = -1e30f;
    #pragma unroll
    for (int i = 0; i < 4; ++i) {
        *(float4*)v[i] = *(const float4*)&src[lane * 4 + i * 256];
        #pragma unroll
        for (int j = 0; j < 4; ++j) m = fmaxf(m, v[i][j]);
    }
    #pragma unroll
    for (int off = 32; off; off >>= 1) m = fmaxf(m, __shfl_xor(m, off));

    float sum = 0.f;
    #pragma unroll
    for (int i = 0; i < 4; ++i)
        #pragma unroll
        for (int j = 0; j < 4; ++j) {
            v[i][j] = __expf(v[i][j] - m);
            sum += v[i][j];
        }
    #pragma unroll
    for (int off = 32; off; off >>= 1) sum += __shfl_xor(sum, off);

    const float inv = 1.f / sum;
    float* dst = attn + (size_t)row * Sc;
    #pragma unroll
    for (int i = 0; i < 4; ++i) {
        float4 o = make_float4(v[i][0] * inv, v[i][1] * inv, v[i][2] * inv, v[i][3] * inv);
        *(float4*)&dst[lane * 4 + i * 256] = o;
    }
}

// ---------------------------------------------------------------------------
// K3: O = attn @ V, written directly in (B, S, H*HD) transposed layout to ws.
// grid: dim3(8, 32) = (S/128, B*H), block 256. Per-thread 8x4 tile.
// ---------------------------------------------------------------------------
__global__ __launch_bounds__(256, 2) void k_pv(
    const float* __restrict__ attn, const float* __restrict__ V,
    float* __restrict__ Omid)
{
    __shared__ float As[128][64];
    __shared__ float Vs[64][64];

    const int bh = blockIdx.y;
    const int b  = bh >> 4;
    const int h  = bh & 15;
    const int qt = blockIdx.x * 128;

    const float* Arow  = attn + ((size_t)bh * Sc + qt) * Sc;
    const float* Vbase = V + (size_t)b * Sc * Ec + (size_t)h * Sc * HDc;

    const int tid = threadIdx.x;
    const int ty = tid >> 4, tx = tid & 15;

    float acc[8][4] = {};

    for (int k0 = 0; k0 < Sc; k0 += 64) {
        #pragma unroll
        for (int i = 0; i < 8; ++i) {
            int idx = tid + i * 256; int r = idx >> 4; int c = (idx & 15) << 2;
            *(float4*)&As[r][c] = *(const float4*)&Arow[(size_t)r * Sc + k0 + c];
        }
        #pragma unroll
        for (int i = 0; i < 4; ++i) {
            int idx = tid + i * 256; int r = idx >> 4; int c = (idx & 15) << 2;
            *(float4*)&Vs[r][c] = *(const float4*)&Vbase[(size_t)(k0 + r) * HDc + c];
        }
        __syncthreads();

        #pragma unroll
        for (int kk = 0; kk < 64; kk += 4) {
            float a4[8][4];
            #pragma unroll
            for (int r = 0; r < 8; ++r)
                *(float4*)a4[r] = *(const float4*)&As[ty * 8 + r][kk];
            #pragma unroll
            for (int j = 0; j < 4; ++j) {
                float4 vv = *(const float4*)&Vs[kk + j][tx * 4];
                #pragma unroll
                for (int r = 0; r < 8; ++r) {
                    acc[r][0] += a4[r][j] * vv.x;
                    acc[r][1] += a4[r][j] * vv.y;
                    acc[r][2] += a4[r][j] * vv.z;
                    acc[r][3] += a4[r][j] * vv.w;
                }
            }
        }
        __syncthreads();
    }

    #pragma unroll
    for (int r = 0; r < 8; ++r) {
        float4 o = make_float4(acc[r][0], acc[r][1], acc[r][2], acc[r][3]);
        *(float4*)&Omid[((size_t)b * Sc + qt + ty * 8 + r) * Ec + h * HDc + tx * 4] = o;
    }
}

// ---------------------------------------------------------------------------
// K4: out = X @ Wo^T + bo. X is (B*S, E) in ws, Wo row-major (E,E).
// grid: dim3(32, 16) = (M/64, E/64), block 256. Per-thread 4x4 tile.
// ---------------------------------------------------------------------------
__global__ __launch_bounds__(256, 2) void k_proj(
    const float* __restrict__ X, const float* __restrict__ Wo,
    const float* __restrict__ bo, float* __restrict__ out)
{
    __shared__ float Xs[64][64];
    __shared__ float Ws[64][64];

    const int mt = blockIdx.x * 64;
    const int et = blockIdx.y * 64;
    const int tid = threadIdx.x;
    const int ty = tid >> 4, tx = tid & 15;

    float acc[4][4] = {};

    for (int k0 = 0; k0 < Ec; k0 += 64) {
        #pragma unroll
        for (int i = 0; i < 4; ++i) {
            int idx = tid + i * 256; int r = idx >> 4; int c = (idx & 15) << 2;
            *(float4*)&Xs[r][c] = *(const float4*)&X[(size_t)(mt + r) * Ec + k0 + c];
            *(float4*)&Ws[r][c] = *(const float4*)&Wo[(size_t)(et + r) * Ec + k0 + c];
        }
        __syncthreads();

        #pragma unroll
        for (int d = 0; d < 64; d += 4) {
            float xa[4][4], wb[4][4];
            #pragma unroll
            for (int r = 0; r < 4; ++r) *(float4*)xa[r] = *(const float4*)&Xs[ty * 4 + r][d];
            #pragma unroll
            for (int c = 0; c < 4; ++c) *(float4*)wb[c] = *(const float4*)&Ws[tx * 4 + c][d];
            #pragma unroll
            for (int r = 0; r < 4; ++r)
                #pragma unroll
                for (int c = 0; c < 4; ++c)
                    #pragma unroll
                    for (int j = 0; j < 4; ++j)
                        acc[r][c] += xa[r][j] * wb[c][j];
        }
        __syncthreads();
    }

    #pragma unroll
    for (int r = 0; r < 4; ++r) {
        float4 o;
        o.x = acc[r][0] + bo[et + tx * 4 + 0];
        o.y = acc[r][1] + bo[et + tx * 4 + 1];
        o.z = acc[r][2] + bo[et + tx * 4 + 2];
        o.w = acc[r][3] + bo[et + tx * 4 + 3];
        *(float4*)&out[(size_t)(mt + ty * 4 + r) * Ec + et + tx * 4] = o;
    }
}

// ---------------------------------------------------------------------------
extern "C" void kernel_launch(void* const* d_in, const int* in_sizes, int n_in,
                              void* d_out, int out_size, void* d_ws, size_t ws_size,
                              hipStream_t stream) {
    const float* query  = (const float*)d_in[0];
    const float* key    = (const float*)d_in[1];
    const float* value  = (const float*)d_in[2];
    const float* aid    = (const float*)d_in[3];
    const float* mw     = (const float*)d_in[4];
    const float* mb     = (const float*)d_in[5];
    const float* Wo     = (const float*)d_in[6];
    const float* bo     = (const float*)d_in[7];
    const float* ascale = (const float*)d_in[8];

    float* out_p  = (float*)d_out;                                   // (B,S,E)
    float* attn_p = out_p + (size_t)Bc * Sc * Ec;                    // (B,H,S,S)
    float* pre_p  = attn_p + (size_t)Bc * Hc * Sc * Sc;              // (B,H,S,S)

    float* Omid = (float*)d_ws;                                      // (B,S,E) f32

    // K1: scores + aid mix -> pre_softmax
    k_scores<<<dim3(64, Bc * Hc), 256, 0, stream>>>(query, key, aid, mw, mb, ascale, pre_p);
    // K2: softmax -> attn
    k_softmax<<<dim3(Bc * Hc * Sc / 4), 256, 0, stream>>>(pre_p, attn_p);
    // K3: attn @ V -> Omid (transposed to (B,S,E))
    k_pv<<<dim3(Sc / 128, Bc * Hc), 256, 0, stream>>>(attn_p, value, Omid);
    // K4: Omid @ Wo^T + bo -> out
    k_proj<<<dim3(Bc * Sc / 64, Ec / 64), 256, 0, stream>>>(Omid, Wo, bo, out_p);
}

// Round 2
// 290.688 us; speedup vs baseline: 2.3055x; 2.3055x over previous
//
#include <hip/hip_runtime.h>
#include <hip/hip_bf16.h>

// Problem constants
constexpr int Bc = 2, Sc = 1024, Ec = 1024, Hc = 16, HDc = 64;
constexpr float SCALE = 0.125f; // HD^-0.5

// XOR swizzle: logical f4-column c4 of row r stored at physical f4-column
// c4 ^ ((r>>2)&15). Keeps 16B alignment; spreads column reads across banks.
__device__ __forceinline__ int swz(int row, int c4) { return c4 ^ ((row >> 2) & 15); }

// ---------------------------------------------------------------------------
// K1: pre_softmax[b,h,q,k] = s + relu(s*w0 + aid·w + bias)*aid_scale,
//     s = (q·k) * SCALE
// grid: dim3(64, 32), block 256. Thread tile 8x8 (rows/cols in 2 groups of 4).
// ---------------------------------------------------------------------------
__global__ __launch_bounds__(256, 2) void k_scores(
    const float* __restrict__ Q, const float* __restrict__ Kp,
    const float* __restrict__ aid, const float* __restrict__ mw,
    const float* __restrict__ mb, const float* __restrict__ ascale,
    float* __restrict__ pre)
{
    __shared__ float Qs[128][64];
    __shared__ float Ks[128][64];

    const int bh = blockIdx.y;
    const int b  = bh >> 4;
    const int h  = bh & 15;
    const int qt = (blockIdx.x >> 3) * 128;
    const int kt = (blockIdx.x & 7) * 128;

    const float* Qbase = Q  + (size_t)b * Sc * Ec + (size_t)h * Sc * HDc;
    const float* Kbase = Kp + (size_t)b * Sc * Ec + (size_t)h * Sc * HDc;

    const int tid = threadIdx.x;

    #pragma unroll
    for (int i = 0; i < 8; ++i) {
        int idx = tid + i * 256;
        int r = idx >> 4;
        int c4 = idx & 15;
        int sc = swz(r, c4);
        *(float4*)&Qs[r][sc * 4] = *(const float4*)&Qbase[(size_t)(qt + r) * HDc + c4 * 4];
        *(float4*)&Ks[r][sc * 4] = *(const float4*)&Kbase[(size_t)(kt + r) * HDc + c4 * 4];
    }
    __syncthreads();

    const int ty = tid >> 4, tx = tid & 15;

    // thread rows: 64*rb + ty*4 + rr ; thread cols: 64*cb + tx*4 + cc
    float acc[8][8] = {};
    #pragma unroll
    for (int d2 = 0; d2 < 16; ++d2) {
        float qv[8][4], kv[8][4];
        #pragma unroll
        for (int r = 0; r < 8; ++r) {
            int row = (r >> 2) * 64 + ty * 4 + (r & 3);
            *(float4*)qv[r] = *(const float4*)&Qs[row][swz(row, d2) * 4];
        }
        #pragma unroll
        for (int c = 0; c < 8; ++c) {
            int col = (c >> 2) * 64 + tx * 4 + (c & 3);
            *(float4*)kv[c] = *(const float4*)&Ks[col][swz(col, d2) * 4];
        }
        #pragma unroll
        for (int r = 0; r < 8; ++r)
            #pragma unroll
            for (int c = 0; c < 8; ++c)
                #pragma unroll
                for (int j = 0; j < 4; ++j)
                    acc[r][c] += qv[r][j] * kv[c][j];
    }

    const float w0 = mw[h * 4 + 0], w1 = mw[h * 4 + 1];
    const float w2 = mw[h * 4 + 2], w3 = mw[h * 4 + 3];
    const float bias = mb[h];
    const float asc  = ascale[0];

    const size_t prebase = (size_t)bh * Sc * Sc;

    #pragma unroll
    for (int r = 0; r < 8; ++r) {
        const int qq = qt + (r >> 2) * 64 + ty * 4 + (r & 3);
        const float* arow = aid + ((size_t)b * Sc + qq) * Sc * 3;
        // two col groups: kt + cb*64 + tx*4 .. +3 ; each needs 12 aid floats
        float a12[2][12];
        #pragma unroll
        for (int cb = 0; cb < 2; ++cb) {
            const float4* src = (const float4*)&arow[(size_t)(kt + cb * 64 + tx * 4) * 3];
            float4* dst4 = (float4*)a12[cb];
            dst4[0] = src[0]; dst4[1] = src[1]; dst4[2] = src[2];
        }
        #pragma unroll
        for (int cb = 0; cb < 2; ++cb) {
            float o[4];
            #pragma unroll
            for (int cc = 0; cc < 4; ++cc) {
                float s = acc[r][cb * 4 + cc] * SCALE;
                float m = s * w0 + a12[cb][cc * 3 + 0] * w1 + a12[cb][cc * 3 + 1] * w2
                        + a12[cb][cc * 3 + 2] * w3 + bias;
                o[cc] = s + fmaxf(m, 0.f) * asc;
            }
            *(float4*)&pre[prebase + (size_t)qq * Sc + kt + cb * 64 + tx * 4] =
                make_float4(o[0], o[1], o[2], o[3]);
        }
    }
}

// ---------------------------------------------------------------------------
// K2: row softmax. One wave per row of 1024. grid: B*H*S/4 blocks, block 256.
// ---------------------------------------------------------------------------
__global__ __launch_bounds__(256) void k_softmax(
    const float* __restrict__ pre, float* __restrict__ attn)
{
    const int row  = blockIdx.x * 4 + (threadIdx.x >> 6);
    const int lane = threadIdx.x & 63;

    const float* src = pre + (size_t)row * Sc;
    float v[4][4];
    float m = -1e30f;
    #pragma unroll
    for (int i = 0; i < 4; ++i) {
        *(float4*)v[i] = *(const float4*)&src[lane * 4 + i * 256];
        #pragma unroll
        for (int j = 0; j < 4; ++j) m = fmaxf(m, v[i][j]);
    }
    #pragma unroll
    for (int off = 32; off; off >>= 1) m = fmaxf(m, __shfl_xor(m, off));

    float sum = 0.f;
    #pragma unroll
    for (int i = 0; i < 4; ++i)
        #pragma unroll
        for (int j = 0; j < 4; ++j) {
            v[i][j] = __expf(v[i][j] - m);
            sum += v[i][j];
        }
    #pragma unroll
    for (int off = 32; off; off >>= 1) sum += __shfl_xor(sum, off);

    const float inv = 1.f / sum;
    float* dst = attn + (size_t)row * Sc;
    #pragma unroll
    for (int i = 0; i < 4; ++i) {
        float4 o = make_float4(v[i][0] * inv, v[i][1] * inv, v[i][2] * inv, v[i][3] * inv);
        *(float4*)&dst[lane * 4 + i * 256] = o;
    }
}

// ---------------------------------------------------------------------------
// K3: O = attn @ V, written in (B, S, H*HD) layout to ws.
// grid: dim3(8, 32), block 256. Thread tile 8x4 (rows in 2 groups of 4).
// ---------------------------------------------------------------------------
__global__ __launch_bounds__(256, 2) void k_pv(
    const float* __restrict__ attn, const float* __restrict__ V,
    float* __restrict__ Omid)
{
    __shared__ float As[128][64];
    __shared__ float Vs[64][64];

    const int bh = blockIdx.y;
    const int b  = bh >> 4;
    const int h  = bh & 15;
    const int qt = blockIdx.x * 128;

    const float* Arow  = attn + ((size_t)bh * Sc + qt) * Sc;
    const float* Vbase = V + (size_t)b * Sc * Ec + (size_t)h * Sc * HDc;

    const int tid = threadIdx.x;
    const int ty = tid >> 4, tx = tid & 15;

    float acc[8][4] = {};

    for (int k0 = 0; k0 < Sc; k0 += 64) {
        #pragma unroll
        for (int i = 0; i < 8; ++i) {
            int idx = tid + i * 256; int r = idx >> 4; int c4 = idx & 15;
            *(float4*)&As[r][swz(r, c4) * 4] = *(const float4*)&Arow[(size_t)r * Sc + k0 + c4 * 4];
        }
        #pragma unroll
        for (int i = 0; i < 4; ++i) {
            int idx = tid + i * 256; int r = idx >> 4; int c = (idx & 15) << 2;
            *(float4*)&Vs[r][c] = *(const float4*)&Vbase[(size_t)(k0 + r) * HDc + c];
        }
        __syncthreads();

        #pragma unroll
        for (int d2 = 0; d2 < 16; ++d2) {
            float a4[8][4];
            #pragma unroll
            for (int r = 0; r < 8; ++r) {
                int row = (r >> 2) * 64 + ty * 4 + (r & 3);
                *(float4*)a4[r] = *(const float4*)&As[row][swz(row, d2) * 4];
            }
            #pragma unroll
            for (int j = 0; j < 4; ++j) {
                float4 vv = *(const float4*)&Vs[d2 * 4 + j][tx * 4];
                #pragma unroll
                for (int r = 0; r < 8; ++r) {
                    acc[r][0] += a4[r][j] * vv.x;
                    acc[r][1] += a4[r][j] * vv.y;
                    acc[r][2] += a4[r][j] * vv.z;
                    acc[r][3] += a4[r][j] * vv.w;
                }
            }
        }
        __syncthreads();
    }

    #pragma unroll
    for (int r = 0; r < 8; ++r) {
        int qq = qt + (r >> 2) * 64 + ty * 4 + (r & 3);
        float4 o = make_float4(acc[r][0], acc[r][1], acc[r][2], acc[r][3]);
        *(float4*)&Omid[((size_t)b * Sc + qq) * Ec + h * HDc + tx * 4] = o;
    }
}

// ---------------------------------------------------------------------------
// K4: out = X @ Wo^T + bo. X is (B*S, E) in ws, Wo row-major (E,E).
// grid: dim3(32, 16), block 256. Per-thread 4x4 tile. Swizzled LDS.
// ---------------------------------------------------------------------------
__global__ __launch_bounds__(256, 2) void k_proj(
    const float* __restrict__ X, const float* __restrict__ Wo,
    const float* __restrict__ bo, float* __restrict__ out)
{
    __shared__ float Xs[64][64];
    __shared__ float Ws[64][64];

    const int mt = blockIdx.x * 64;
    const int et = blockIdx.y * 64;
    const int tid = threadIdx.x;
    const int ty = tid >> 4, tx = tid & 15;

    float acc[4][4] = {};

    for (int k0 = 0; k0 < Ec; k0 += 64) {
        #pragma unroll
        for (int i = 0; i < 4; ++i) {
            int idx = tid + i * 256; int r = idx >> 4; int c4 = idx & 15;
            int sc = swz(r, c4);
            *(float4*)&Xs[r][sc * 4] = *(const float4*)&X[(size_t)(mt + r) * Ec + k0 + c4 * 4];
            *(float4*)&Ws[r][sc * 4] = *(const float4*)&Wo[(size_t)(et + r) * Ec + k0 + c4 * 4];
        }
        __syncthreads();

        #pragma unroll
        for (int d2 = 0; d2 < 16; ++d2) {
            float xa[4][4], wb[4][4];
            #pragma unroll
            for (int r = 0; r < 4; ++r) {
                int row = ty * 4 + r;
                *(float4*)xa[r] = *(const float4*)&Xs[row][swz(row, d2) * 4];
            }
            #pragma unroll
            for (int c = 0; c < 4; ++c) {
                int row = tx * 4 + c;
                *(float4*)wb[c] = *(const float4*)&Ws[row][swz(row, d2) * 4];
            }
            #pragma unroll
            for (int r = 0; r < 4; ++r)
                #pragma unroll
                for (int c = 0; c < 4; ++c)
                    #pragma unroll
                    for (int j = 0; j < 4; ++j)
                        acc[r][c] += xa[r][j] * wb[c][j];
        }
        __syncthreads();
    }

    #pragma unroll
    for (int r = 0; r < 4; ++r) {
        float4 o;
        o.x = acc[r][0] + bo[et + tx * 4 + 0];
        o.y = acc[r][1] + bo[et + tx * 4 + 1];
        o.z = acc[r][2] + bo[et + tx * 4 + 2];
        o.w = acc[r][3] + bo[et + tx * 4 + 3];
        *(float4*)&out[(size_t)(mt + ty * 4 + r) * Ec + et + tx * 4] = o;
    }
}

// ---------------------------------------------------------------------------
extern "C" void kernel_launch(void* const* d_in, const int* in_sizes, int n_in,
                              void* d_out, int out_size, void* d_ws, size_t ws_size,
                              hipStream_t stream) {
    const float* query  = (const float*)d_in[0];
    const float* key    = (const float*)d_in[1];
    const float* value  = (const float*)d_in[2];
    const float* aid    = (const float*)d_in[3];
    const float* mw     = (const float*)d_in[4];
    const float* mb     = (const float*)d_in[5];
    const float* Wo     = (const float*)d_in[6];
    const float* bo     = (const float*)d_in[7];
    const float* ascale = (const float*)d_in[8];

    float* out_p  = (float*)d_out;                                   // (B,S,E)
    float* attn_p = out_p + (size_t)Bc * Sc * Ec;                    // (B,H,S,S)
    float* pre_p  = attn_p + (size_t)Bc * Hc * Sc * Sc;              // (B,H,S,S)

    float* Omid = (float*)d_ws;                                      // (B,S,E) f32

    k_scores<<<dim3(64, Bc * Hc), 256, 0, stream>>>(query, key, aid, mw, mb, ascale, pre_p);
    k_softmax<<<dim3(Bc * Hc * Sc / 4), 256, 0, stream>>>(pre_p, attn_p);
    k_pv<<<dim3(Sc / 128, Bc * Hc), 256, 0, stream>>>(attn_p, value, Omid);
    k_proj<<<dim3(Bc * Sc / 64, Ec / 64), 256, 0, stream>>>(Omid, Wo, bo, out_p);
}

// Round 3
// 214.241 us; speedup vs baseline: 3.1282x; 1.3568x over previous
//
#include <hip/hip_runtime.h>
#include <hip/hip_bf16.h>

using u16 = unsigned short;
typedef __attribute__((ext_vector_type(8))) short short8;   // 8 bf16 = 4 VGPR
typedef __attribute__((ext_vector_type(4))) float f32x4;

constexpr int Bc = 2, Sc = 1024, Ec = 1024, Hc = 16, HDc = 64;
constexpr float SCALE = 0.125f; // HD^-0.5

// f32 -> bf16 round-to-nearest-even
__device__ __forceinline__ u16 f2bf(float f) {
    union { float f; unsigned u; } v{f};
    unsigned r = v.u + 0x7FFF + ((v.u >> 16) & 1);
    return (u16)(r >> 16);
}

// ---------------------------------------------------------------------------
// P0: f32 -> bf16 copy (layout preserved). n multiple of 2048.
// ---------------------------------------------------------------------------
__global__ __launch_bounds__(256) void k_conv(const float* __restrict__ src,
                                              u16* __restrict__ dst) {
    int i = (blockIdx.x * 256 + threadIdx.x) * 8;
    float4 a = *(const float4*)&src[i];
    float4 b = *(const float4*)&src[i + 4];
    u16 t[8] = {f2bf(a.x), f2bf(a.y), f2bf(a.z), f2bf(a.w),
                f2bf(b.x), f2bf(b.y), f2bf(b.z), f2bf(b.w)};
    *(short8*)&dst[i] = *(short8*)t;
}

// ---------------------------------------------------------------------------
// P0b: V (B,H,S,HD panels) -> Vt[bh][d=64][S=1024] bf16 (transposed).
// grid (S/64, B*H), block 256.
// ---------------------------------------------------------------------------
__global__ __launch_bounds__(256) void k_convT(const float* __restrict__ V,
                                               u16* __restrict__ Vt) {
    __shared__ float tile[64][65];
    const int bh = blockIdx.y;
    const int k0 = blockIdx.x * 64;
    const float* Vp = V + (size_t)bh * Sc * HDc + (size_t)k0 * HDc;
    const int tid = threadIdx.x;

    #pragma unroll
    for (int it = 0; it < 4; ++it) {
        int idx = tid + it * 256;
        int k = idx >> 4, d4 = idx & 15;
        float4 v = *(const float4*)&Vp[k * HDc + d4 * 4];
        tile[d4 * 4 + 0][k] = v.x;
        tile[d4 * 4 + 1][k] = v.y;
        tile[d4 * 4 + 2][k] = v.z;
        tile[d4 * 4 + 3][k] = v.w;
    }
    __syncthreads();

    u16* Op = Vt + (size_t)bh * HDc * Sc + k0;
    #pragma unroll
    for (int it = 0; it < 4; ++it) {
        int idx = tid + it * 256;
        int d = idx >> 4, kq = idx & 15;
        u16 t[4];
        #pragma unroll
        for (int j = 0; j < 4; ++j) t[j] = f2bf(tile[d][kq * 4 + j]);
        *(uint2*)&Op[(size_t)d * Sc + kq * 4] = *(uint2*)t;
    }
}

// ---------------------------------------------------------------------------
// K1: scores + aid-mixer -> pre (f32). MFMA 16x16x32 bf16.
// 1D grid: bid = ((b*8+qt)*8+kt)*16 + h  (h fastest for aid L2 sharing)
// block 256 = 4 waves, each computes a 64x64 quadrant of the 128x128 tile.
// ---------------------------------------------------------------------------
__global__ __launch_bounds__(256, 2) void k_scores(
    const u16* __restrict__ Qb, const u16* __restrict__ Kb,
    const float* __restrict__ aid, const float* __restrict__ mw,
    const float* __restrict__ mb, const float* __restrict__ ascale,
    float* __restrict__ pre)
{
    __shared__ u16 Qs[128 * 64];
    __shared__ u16 Ks[128 * 64];

    const int bid = blockIdx.x;
    const int h  = bid & 15;
    const int kt = (bid >> 4) & 7;
    const int qt = (bid >> 7) & 7;
    const int b  = bid >> 10;

    const u16* Qp = Qb + (size_t)(b * Hc + h) * Sc * HDc + (size_t)qt * 128 * HDc;
    const u16* Kp = Kb + (size_t)(b * Hc + h) * Sc * HDc + (size_t)kt * 128 * HDc;

    const int tid = threadIdx.x;

    // stage 128x64 bf16 tiles, 16B granules, XOR swizzle g^(r&7)
    #pragma unroll
    for (int it = 0; it < 4; ++it) {
        int idx = tid + it * 256;      // 0..1023 granules
        int r = idx >> 3, g = idx & 7;
        int gs = g ^ (r & 7);
        *(short8*)&Qs[r * 64 + gs * 8] = *(const short8*)&Qp[r * 64 + g * 8];
        *(short8*)&Ks[r * 64 + gs * 8] = *(const short8*)&Kp[r * 64 + g * 8];
    }
    __syncthreads();

    const int w = tid >> 6, lane = tid & 63;
    const int wq = (w >> 1) * 64, wk = (w & 1) * 64;
    const int lrow = lane & 15, lhi = lane >> 4;

    f32x4 acc[4][4] = {};
    #pragma unroll
    for (int ks = 0; ks < 2; ++ks) {
        short8 af[4], bfr[4];
        #pragma unroll
        for (int f = 0; f < 4; ++f) {
            int rq = wq + f * 16 + lrow;
            int g  = ks * 4 + lhi;
            af[f]  = *(const short8*)&Qs[rq * 64 + (g ^ (rq & 7)) * 8];
            int rk = wk + f * 16 + lrow;
            bfr[f] = *(const short8*)&Ks[rk * 64 + (g ^ (rk & 7)) * 8];
        }
        #pragma unroll
        for (int fq = 0; fq < 4; ++fq)
            #pragma unroll
            for (int fk = 0; fk < 4; ++fk)
                acc[fq][fk] = __builtin_amdgcn_mfma_f32_16x16x32_bf16(
                    af[fq], bfr[fk], acc[fq][fk], 0, 0, 0);
    }

    const float w0 = mw[h * 4 + 0], w1 = mw[h * 4 + 1];
    const float w2 = mw[h * 4 + 2], w3 = mw[h * 4 + 3];
    const float bias = mb[h];
    const float asc  = ascale[0];
    const size_t prebase = (size_t)(b * Hc + h) * Sc * Sc;

    #pragma unroll
    for (int fq = 0; fq < 4; ++fq) {
        #pragma unroll
        for (int r = 0; r < 4; ++r) {
            const int q = qt * 128 + wq + fq * 16 + lhi * 4 + r;
            const float* arow = aid + (size_t)(b * Sc + q) * Sc * 3;
            float* prow = pre + prebase + (size_t)q * Sc;
            #pragma unroll
            for (int fk = 0; fk < 4; ++fk) {
                const int k = kt * 128 + wk + fk * 16 + lrow;
                float s = acc[fq][fk][r] * SCALE;
                const float* ap = arow + (size_t)k * 3;
                float m = s * w0 + ap[0] * w1 + ap[1] * w2 + ap[2] * w3 + bias;
                prow[k] = s + fmaxf(m, 0.f) * asc;
            }
        }
    }
}

// ---------------------------------------------------------------------------
// K2: row softmax (f32 in/out). One wave per row. grid B*H*S/4, block 256.
// ---------------------------------------------------------------------------
__global__ __launch_bounds__(256) void k_softmax(
    const float* __restrict__ pre, float* __restrict__ attn)
{
    const int row  = blockIdx.x * 4 + (threadIdx.x >> 6);
    const int lane = threadIdx.x & 63;

    const float* src = pre + (size_t)row * Sc;
    float v[4][4];
    float m = -1e30f;
    #pragma unroll
    for (int i = 0; i < 4; ++i) {
        *(float4*)v[i] = *(const float4*)&src[lane * 4 + i * 256];
        #pragma unroll
        for (int j = 0; j < 4; ++j) m = fmaxf(m, v[i][j]);
    }
    #pragma unroll
    for (int off = 32; off; off >>= 1) m = fmaxf(m, __shfl_xor(m, off));

    float sum = 0.f;
    #pragma unroll
    for (int i = 0; i < 4; ++i)
        #pragma unroll
        for (int j = 0; j < 4; ++j) {
            v[i][j] = __expf(v[i][j] - m);
            sum += v[i][j];
        }
    #pragma unroll
    for (int off = 32; off; off >>= 1) sum += __shfl_xor(sum, off);

    const float inv = 1.f / sum;
    float* dst = attn + (size_t)row * Sc;
    #pragma unroll
    for (int i = 0; i < 4; ++i) {
        float4 o = make_float4(v[i][0] * inv, v[i][1] * inv, v[i][2] * inv, v[i][3] * inv);
        *(float4*)&dst[lane * 4 + i * 256] = o;
    }
}

// ---------------------------------------------------------------------------
// K3: Omid(bf16) = attn @ V. A = attn (f32->bf16 at staging), B = Vt[d][k].
// grid (S/128, B*H), block 256 = 4 waves; wave = 32 q-rows x 64 d.
// ---------------------------------------------------------------------------
__global__ __launch_bounds__(256, 2) void k_pv(
    const float* __restrict__ attn, const u16* __restrict__ Vt,
    u16* __restrict__ Omid)
{
    __shared__ u16 As[128 * 64];
    __shared__ u16 Vs[64 * 64];

    const int bh = blockIdx.y;
    const int b  = bh >> 4, h = bh & 15;
    const int qt = blockIdx.x * 128;

    const float* Ab = attn + ((size_t)bh * Sc + qt) * Sc;
    const u16*   Vp = Vt + (size_t)bh * HDc * Sc;

    const int tid = threadIdx.x;
    const int w = tid >> 6, lane = tid & 63;
    const int lrow = lane & 15, lhi = lane >> 4;

    f32x4 acc[2][4] = {};

    for (int kb = 0; kb < Sc; kb += 64) {
        // stage A: 128 rows x 64 k, f32 -> bf16, swizzled granules
        #pragma unroll
        for (int it = 0; it < 4; ++it) {
            int idx = tid + it * 256;
            int r = idx >> 3, g = idx & 7;
            const float* srcp = Ab + (size_t)r * Sc + kb + g * 8;
            float4 a = *(const float4*)srcp;
            float4 c = *(const float4*)(srcp + 4);
            u16 t[8] = {f2bf(a.x), f2bf(a.y), f2bf(a.z), f2bf(a.w),
                        f2bf(c.x), f2bf(c.y), f2bf(c.z), f2bf(c.w)};
            *(short8*)&As[r * 64 + (g ^ (r & 7)) * 8] = *(short8*)t;
        }
        // stage Vt tile: 64 d-rows x 64 k
        #pragma unroll
        for (int it = 0; it < 2; ++it) {
            int idx = tid + it * 256;
            int r = idx >> 3, g = idx & 7;
            *(short8*)&Vs[r * 64 + (g ^ (r & 7)) * 8] =
                *(const short8*)&Vp[(size_t)r * Sc + kb + g * 8];
        }
        __syncthreads();

        #pragma unroll
        for (int ks = 0; ks < 2; ++ks) {
            short8 af[2], bfr[4];
            int g = ks * 4 + lhi;
            #pragma unroll
            for (int fq = 0; fq < 2; ++fq) {
                int rq = w * 32 + fq * 16 + lrow;
                af[fq] = *(const short8*)&As[rq * 64 + (g ^ (rq & 7)) * 8];
            }
            #pragma unroll
            for (int fd = 0; fd < 4; ++fd) {
                int rv = fd * 16 + lrow;
                bfr[fd] = *(const short8*)&Vs[rv * 64 + (g ^ (rv & 7)) * 8];
            }
            #pragma unroll
            for (int fq = 0; fq < 2; ++fq)
                #pragma unroll
                for (int fd = 0; fd < 4; ++fd)
                    acc[fq][fd] = __builtin_amdgcn_mfma_f32_16x16x32_bf16(
                        af[fq], bfr[fd], acc[fq][fd], 0, 0, 0);
        }
        __syncthreads();
    }

    // Omid[(b*S + q)][h*64 + d] bf16
    #pragma unroll
    for (int fq = 0; fq < 2; ++fq)
        #pragma unroll
        for (int r = 0; r < 4; ++r) {
            const int q = qt + w * 32 + fq * 16 + lhi * 4 + r;
            u16* orow = Omid + ((size_t)b * Sc + q) * Ec + h * HDc;
            #pragma unroll
            for (int fd = 0; fd < 4; ++fd)
                orow[fd * 16 + lrow] = f2bf(acc[fq][fd][r]);
        }
}

// ---------------------------------------------------------------------------
// K4: out = Omid @ Wo^T + bo (f32 out). A = Omid bf16, B = Wob bf16.
// 1D grid 256: mt = (bid>>4)*128, et = (bid&15)*64. block 256 = 4 waves.
// ---------------------------------------------------------------------------
__global__ __launch_bounds__(256, 2) void k_proj(
    const u16* __restrict__ Ob, const u16* __restrict__ Wob,
    const float* __restrict__ bo, float* __restrict__ out)
{
    __shared__ u16 Xs[128 * 64];
    __shared__ u16 Ws[64 * 64];

    const int bid = blockIdx.x;
    const int mt = (bid >> 4) * 128;
    const int et = (bid & 15) * 64;

    const int tid = threadIdx.x;
    const int w = tid >> 6, lane = tid & 63;
    const int lrow = lane & 15, lhi = lane >> 4;

    f32x4 acc[2][4] = {};

    for (int kb = 0; kb < Ec; kb += 64) {
        #pragma unroll
        for (int it = 0; it < 4; ++it) {
            int idx = tid + it * 256;
            int r = idx >> 3, g = idx & 7;
            *(short8*)&Xs[r * 64 + (g ^ (r & 7)) * 8] =
                *(const short8*)&Ob[(size_t)(mt + r) * Ec + kb + g * 8];
        }
        #pragma unroll
        for (int it = 0; it < 2; ++it) {
            int idx = tid + it * 256;
            int r = idx >> 3, g = idx & 7;
            *(short8*)&Ws[r * 64 + (g ^ (r & 7)) * 8] =
                *(const short8*)&Wob[(size_t)(et + r) * Ec + kb + g * 8];
        }
        __syncthreads();

        #pragma unroll
        for (int ks = 0; ks < 2; ++ks) {
            short8 af[2], bfr[4];
            int g = ks * 4 + lhi;
            #pragma unroll
            for (int fq = 0; fq < 2; ++fq) {
                int rq = w * 32 + fq * 16 + lrow;
                af[fq] = *(const short8*)&Xs[rq * 64 + (g ^ (rq & 7)) * 8];
            }
            #pragma unroll
            for (int fd = 0; fd < 4; ++fd) {
                int rv = fd * 16 + lrow;
                bfr[fd] = *(const short8*)&Ws[rv * 64 + (g ^ (rv & 7)) * 8];
            }
            #pragma unroll
            for (int fq = 0; fq < 2; ++fq)
                #pragma unroll
                for (int fd = 0; fd < 4; ++fd)
                    acc[fq][fd] = __builtin_amdgcn_mfma_f32_16x16x32_bf16(
                        af[fq], bfr[fd], acc[fq][fd], 0, 0, 0);
        }
        __syncthreads();
    }

    #pragma unroll
    for (int fq = 0; fq < 2; ++fq)
        #pragma unroll
        for (int r = 0; r < 4; ++r) {
            const int m = mt + w * 32 + fq * 16 + lhi * 4 + r;
            float* orow = out + (size_t)m * Ec + et;
            #pragma unroll
            for (int fd = 0; fd < 4; ++fd) {
                int e = fd * 16 + lrow;
                orow[e] = acc[fq][fd][r] + bo[et + e];
            }
        }
}

// ---------------------------------------------------------------------------
extern "C" void kernel_launch(void* const* d_in, const int* in_sizes, int n_in,
                              void* d_out, int out_size, void* d_ws, size_t ws_size,
                              hipStream_t stream) {
    const float* query  = (const float*)d_in[0];
    const float* key    = (const float*)d_in[1];
    const float* value  = (const float*)d_in[2];
    const float* aid    = (const float*)d_in[3];
    const float* mw     = (const float*)d_in[4];
    const float* mb     = (const float*)d_in[5];
    const float* Wo     = (const float*)d_in[6];
    const float* bo     = (const float*)d_in[7];
    const float* ascale = (const float*)d_in[8];

    float* out_p  = (float*)d_out;                       // (B,S,E)
    float* attn_p = out_p + (size_t)Bc * Sc * Ec;        // (B,H,S,S)
    float* pre_p  = attn_p + (size_t)Bc * Hc * Sc * Sc;  // (B,H,S,S)

    // ws layout (bf16 buffers)
    u16* Qb  = (u16*)d_ws;                    // 2M elems, 4 MB
    u16* Kb  = Qb + (size_t)2 * 1024 * 1024;  // 4 MB
    u16* Wob = Kb + (size_t)2 * 1024 * 1024;  // 2 MB
    u16* Vtb = Wob + (size_t)1024 * 1024;     // 4 MB (transposed V)
    u16* Omid = Vtb + (size_t)2 * 1024 * 1024; // 4 MB

    const int nQ = Bc * Sc * Ec;  // 2M
    k_conv<<<nQ / 2048, 256, 0, stream>>>(query, Qb);
    k_conv<<<nQ / 2048, 256, 0, stream>>>(key, Kb);
    k_conv<<<(Ec * Ec) / 2048, 256, 0, stream>>>(Wo, Wob);
    k_convT<<<dim3(Sc / 64, Bc * Hc), 256, 0, stream>>>(value, Vtb);

    k_scores<<<Bc * 8 * 8 * Hc, 256, 0, stream>>>(Qb, Kb, aid, mw, mb, ascale, pre_p);
    k_softmax<<<Bc * Hc * Sc / 4, 256, 0, stream>>>(pre_p, attn_p);
    k_pv<<<dim3(Sc / 128, Bc * Hc), 256, 0, stream>>>(attn_p, Vtb, Omid);
    k_proj<<<(Bc * Sc / 128) * (Ec / 64), 256, 0, stream>>>(Omid, Wob, bo, out_p);
}